// Round 1
// baseline (1253.856 us; speedup 1.0000x reference)
//
#include <hip/hip_runtime.h>

#define D 128

// ---------------- utility ----------------
__global__ void zero_kernel(int* p, int nwords) {
    int i = blockIdx.x * 256 + threadIdx.x;
    if (i < nwords) p[i] = 0;
}

// ---------------- degree histogram ----------------
__global__ void k_degree(const int* __restrict__ dst, int* __restrict__ deg, int E) {
    int i = blockIdx.x * 256 + threadIdx.x;
    if (i < E) atomicAdd(&deg[dst[i]], 1);
}

__global__ void k_dinv(const int* __restrict__ deg, float* __restrict__ dinv, int n) {
    int i = blockIdx.x * 256 + threadIdx.x;
    if (i < n) dinv[i] = rsqrtf((float)(deg[i] + 1));  // +1 self-loop; always > 0
}

// ow[i] = sum over out-edges of dinv[dst]
__global__ void k_ow(const int* __restrict__ src, const int* __restrict__ dst,
                     const float* __restrict__ dinv, float* __restrict__ ow, int E) {
    int i = blockIdx.x * 256 + threadIdx.x;
    if (i < E) atomicAdd(&ow[src[i]], dinv[dst[i]]);
}

__global__ void k_cvec(const float* __restrict__ dinv, const float* __restrict__ ow,
                       float* __restrict__ cvec, int n) {
    int i = blockIdx.x * 256 + threadIdx.x;
    if (i < n) cvec[i] = dinv[i] * (dinv[i] + ow[i]);
}

// ---------------- exclusive scan (3-phase) ----------------
__global__ void scan1(const int* __restrict__ cnt, int* __restrict__ excl,
                      int* __restrict__ bsum, int n) {
    __shared__ int s[256];
    int tx = threadIdx.x;
    int i = blockIdx.x * 256 + tx;
    int v = (i < n) ? cnt[i] : 0;
    s[tx] = v;
    __syncthreads();
    for (int d = 1; d < 256; d <<= 1) {
        int t = (tx >= d) ? s[tx - d] : 0;
        __syncthreads();
        s[tx] += t;
        __syncthreads();
    }
    if (i < n) excl[i] = s[tx] - v;
    if (tx == 255) bsum[blockIdx.x] = s[255];
}

__global__ void scan2(int* __restrict__ bsum, int nb) {
    __shared__ int s[512];
    int tx = threadIdx.x;
    int v = (tx < nb) ? bsum[tx] : 0;
    s[tx] = v;
    __syncthreads();
    for (int d = 1; d < 512; d <<= 1) {
        int t = (tx >= d) ? s[tx - d] : 0;
        __syncthreads();
        s[tx] += t;
        __syncthreads();
    }
    if (tx < nb) bsum[tx] = s[tx] - v;  // exclusive
}

__global__ void scan3(int* __restrict__ row_ptr, const int* __restrict__ bsum,
                      int n, int E) {
    int i = blockIdx.x * 256 + threadIdx.x;
    if (i < n) row_ptr[i] += bsum[i >> 8];
    else if (i == n) row_ptr[n] = E;
}

// ---------------- CSR fill ----------------
__global__ void k_fill(const int* __restrict__ src, const int* __restrict__ dst,
                       const int* __restrict__ row_ptr, int* __restrict__ cursor,
                       const float* __restrict__ dinv,
                       int* __restrict__ csr_src, float* __restrict__ csr_norm, int E) {
    int i = blockIdx.x * 256 + threadIdx.x;
    if (i >= E) return;
    int d = dst[i];
    int s = src[i];
    int pos = row_ptr[d] + atomicAdd(&cursor[d], 1);
    csr_src[pos] = s;
    csr_norm[pos] = dinv[s] * dinv[d];
}

// ---------------- GEMM: C[n,128] = A[n,128] @ W[128,128] ----------------
// 256 threads: 32 col-groups x 8 row-groups, each thread 4 rows x 4 cols.
__launch_bounds__(256)
__global__ void gemm128(const float* __restrict__ A, const float* __restrict__ W,
                        float* __restrict__ C, int nrows) {
    int cg = threadIdx.x & 31;
    int rg = threadIdx.x >> 5;
    int r0 = blockIdx.x * 32 + rg * 4;
    float acc[4][4];
#pragma unroll
    for (int i = 0; i < 4; i++)
#pragma unroll
        for (int j = 0; j < 4; j++) acc[i][j] = 0.f;

    int r[4];
#pragma unroll
    for (int i = 0; i < 4; i++) r[i] = min(r0 + i, nrows - 1);  // clamp (N%32==0 anyway)

    for (int k = 0; k < D; k += 4) {
        float4 w0 = *(const float4*)(W + (size_t)(k + 0) * D + cg * 4);
        float4 w1 = *(const float4*)(W + (size_t)(k + 1) * D + cg * 4);
        float4 w2 = *(const float4*)(W + (size_t)(k + 2) * D + cg * 4);
        float4 w3 = *(const float4*)(W + (size_t)(k + 3) * D + cg * 4);
#pragma unroll
        for (int i = 0; i < 4; i++) {
            float4 a = *(const float4*)(A + (size_t)r[i] * D + k);
            acc[i][0] += a.x * w0.x + a.y * w1.x + a.z * w2.x + a.w * w3.x;
            acc[i][1] += a.x * w0.y + a.y * w1.y + a.z * w2.y + a.w * w3.y;
            acc[i][2] += a.x * w0.z + a.y * w1.z + a.z * w2.z + a.w * w3.z;
            acc[i][3] += a.x * w0.w + a.y * w1.w + a.z * w2.w + a.w * w3.w;
        }
    }
#pragma unroll
    for (int i = 0; i < 4; i++) {
        if (r0 + i < nrows) {
            float4 o;
            o.x = acc[i][0]; o.y = acc[i][1]; o.z = acc[i][2]; o.w = acc[i][3];
            *(float4*)(C + (size_t)(r0 + i) * D + cg * 4) = o;
        }
    }
}

// ---------------- aggregation: out[n] = relu?(bias + dinv[n]^2*t[n] + sum_e norm*t[src]) -----
// one wave (64 lanes) per node, float2 per lane covers the 128-f row.
__launch_bounds__(256)
__global__ void agg_kernel(const float* __restrict__ t, const int* __restrict__ csr_src,
                           const float* __restrict__ csr_norm, const int* __restrict__ row_ptr,
                           const float* __restrict__ dinv, const float* __restrict__ bias,
                           float* __restrict__ out, int n, int do_relu) {
    int node = blockIdx.x * 4 + (threadIdx.x >> 6);
    if (node >= n) return;
    int lane = threadIdx.x & 63;
    int c = lane * 2;

    int beg = row_ptr[node];
    int end = row_ptr[node + 1];
    float dn = dinv[node];

    float2 self = *(const float2*)(t + (size_t)node * D + c);
    float ax = dn * dn * self.x;
    float ay = dn * dn * self.y;

    int e = beg;
    for (; e + 4 <= end; e += 4) {
        int s0 = csr_src[e], s1 = csr_src[e + 1], s2 = csr_src[e + 2], s3 = csr_src[e + 3];
        float n0 = csr_norm[e], n1 = csr_norm[e + 1], n2 = csr_norm[e + 2], n3 = csr_norm[e + 3];
        float2 f0 = *(const float2*)(t + (size_t)s0 * D + c);
        float2 f1 = *(const float2*)(t + (size_t)s1 * D + c);
        float2 f2 = *(const float2*)(t + (size_t)s2 * D + c);
        float2 f3 = *(const float2*)(t + (size_t)s3 * D + c);
        ax += n0 * f0.x + n1 * f1.x + n2 * f2.x + n3 * f3.x;
        ay += n0 * f0.y + n1 * f1.y + n2 * f2.y + n3 * f3.y;
    }
    for (; e < end; ++e) {
        int s = csr_src[e];
        float nw = csr_norm[e];
        float2 f = *(const float2*)(t + (size_t)s * D + c);
        ax += nw * f.x;
        ay += nw * f.y;
    }
    ax += bias[c];
    ay += bias[c + 1];
    if (do_relu) { ax = fmaxf(ax, 0.f); ay = fmaxf(ay, 0.f); }
    float2 o; o.x = ax; o.y = ay;
    *(float2*)(out + (size_t)node * D + c) = o;
}

// ---------------- weighted reduce: v[c] += sum_i cvec[i] * h[i][c] ----------------
__launch_bounds__(256)
__global__ void wreduce(const float* __restrict__ h, const float* __restrict__ cvec,
                        float* __restrict__ v, int n) {
    __shared__ float s[256];
    int c = threadIdx.x & 127;
    int half = threadIdx.x >> 7;
    int base = blockIdx.x * 256;
    int lim = min(base + 256, n);
    float acc = 0.f;
    for (int r = base + half; r < lim; r += 2)
        acc += cvec[r] * h[(size_t)r * D + c];
    s[threadIdx.x] = acc;
    __syncthreads();
    if (threadIdx.x < 128) atomicAdd(&v[c], s[threadIdx.x] + s[threadIdx.x + 128]);
}

// ---------------- finalize: out[j] = (v @ w3)[j]/N + b3[j] ----------------
__global__ void finalize(const float* __restrict__ v, const float* __restrict__ w3,
                         const float* __restrict__ b3, float* __restrict__ out, float invn) {
    __shared__ float sv[D];
    int j = threadIdx.x;
    sv[j] = v[j];
    __syncthreads();
    float acc = 0.f;
    for (int k = 0; k < D; k++) acc += sv[k] * w3[(size_t)k * D + j];
    out[j] = acc * invn + b3[j];
}

extern "C" void kernel_launch(void* const* d_in, const int* in_sizes, int n_in,
                              void* d_out, int out_size, void* d_ws, size_t ws_size,
                              hipStream_t stream) {
    const float* x   = (const float*)d_in[0];
    const int*   ei  = (const int*)d_in[1];
    const float* w1  = (const float*)d_in[2];
    const float* b1  = (const float*)d_in[3];
    const float* w2  = (const float*)d_in[4];
    const float* b2  = (const float*)d_in[5];
    const float* w3  = (const float*)d_in[6];
    const float* b3  = (const float*)d_in[7];
    float* out = (float*)d_out;

    const int N = in_sizes[0] / D;       // 100000
    const int E = in_sizes[1] / 2;       // 3200000
    const int* src = ei;
    const int* dst = ei + E;

    // ---- workspace layout ----
    char* p = (char*)d_ws;
    auto alloc = [&](size_t bytes) -> char* {
        char* r = p;
        p += (bytes + 255) & ~(size_t)255;
        return r;
    };
    int*   row_ptr  = (int*)alloc((size_t)(N + 1) * 4);
    char*  zbeg     = p;
    int*   deg_cnt  = (int*)alloc((size_t)N * 4);
    int*   cursor   = (int*)alloc((size_t)N * 4);
    float* ow       = (float*)alloc((size_t)N * 4);
    float* v        = (float*)alloc((size_t)D * 4);
    char*  zend     = p;
    float* dinv     = (float*)alloc((size_t)N * 4);
    float* cvec     = (float*)alloc((size_t)N * 4);
    int*   bsum     = (int*)alloc(4096 * 4);
    int*   csr_src  = (int*)alloc((size_t)E * 4);
    float* csr_norm = (float*)alloc((size_t)E * 4);
    float* bufA     = (float*)alloc((size_t)N * D * 4);
    float* bufB     = (float*)alloc((size_t)N * D * 4);
    (void)ws_size;

    const int gN  = (N + 255) / 256;         // 391
    const int gE  = (E + 255) / 256;         // 12500
    const int nb  = gN;                      // scan blocks (must be <= 512)

    // zero deg_cnt/cursor/ow/v
    {
        int zwords = (int)((zend - zbeg) / 4);
        zero_kernel<<<(zwords + 255) / 256, 256, 0, stream>>>((int*)zbeg, zwords);
    }

    // degree + dinv + out-weights
    k_degree<<<gE, 256, 0, stream>>>(dst, deg_cnt, E);
    k_dinv<<<gN, 256, 0, stream>>>(deg_cnt, dinv, N);
    k_ow<<<gE, 256, 0, stream>>>(src, dst, dinv, ow, E);
    k_cvec<<<gN, 256, 0, stream>>>(dinv, ow, cvec, N);

    // CSR: exclusive scan of degrees -> row_ptr, then fill
    scan1<<<nb, 256, 0, stream>>>(deg_cnt, row_ptr, bsum, N);
    scan2<<<1, 512, 0, stream>>>(bsum, nb);
    scan3<<<(N + 256) / 256, 256, 0, stream>>>(row_ptr, bsum, N, E);
    k_fill<<<gE, 256, 0, stream>>>(src, dst, row_ptr, cursor, dinv, csr_src, csr_norm, E);

    // layer 1: t = x@w1 ; h1 = relu(agg(t)+b1)
    gemm128<<<(N + 31) / 32, 256, 0, stream>>>(x, w1, bufA, N);
    agg_kernel<<<(N + 3) / 4, 256, 0, stream>>>(bufA, csr_src, csr_norm, row_ptr, dinv, b1,
                                                bufB, N, 1);
    // layer 2: t = h1@w2 ; h2 = relu(agg(t)+b2)
    gemm128<<<(N + 31) / 32, 256, 0, stream>>>(bufB, w2, bufA, N);
    agg_kernel<<<(N + 3) / 4, 256, 0, stream>>>(bufA, csr_src, csr_norm, row_ptr, dinv, b2,
                                                bufB, N, 1);
    // layer 3 collapsed: v = sum_i cvec[i]*h2[i] ; out = v@w3/N + b3
    wreduce<<<gN, 256, 0, stream>>>(bufB, cvec, v, N);
    finalize<<<1, D, 0, stream>>>(v, w3, b3, out, 1.0f / (float)N);
}